// Round 15
// baseline (92.563 us; speedup 1.0000x reference)
//
#include <hip/hip_runtime.h>

#define F      128
#define RNODES 32
#define NBUCK  1563         // fine buckets: ceil(50000/32)
#define CB     1280         // fine bucket capacity (mean 1024, +8 sigma)
#define OVCAP  65536

// Two-level multisplit parameters
#define CHA    8192         // pass-A chunk (edges)
#define NCB    49           // coarse buckets (1024 nodes each; ceil(50000/1024))
#define CCAP   34304        // coarse capacity (mean 32768, +8.5 sigma)
#define G_PA   196          // pass-A blocks = ceil(1.6M/8192)
#define CHB    8192         // pass-B subchunk
#define NSUB   5            // ceil(CCAP/CHB)

typedef __attribute__((ext_vector_type(8))) short short8;            // 8 bf16
typedef __attribute__((ext_vector_type(4))) float f32x4;             // MFMA C/D

__device__ inline short f2bf(float f) {        // fp32 -> bf16 RNE
  unsigned u = __float_as_uint(f);
  u += 0x7fff + ((u >> 16) & 1);
  return (short)(u >> 16);
}
__device__ inline float bf2f(unsigned short u) {
  return __uint_as_float((unsigned)u << 16);
}

// ---------------------------------------------------------------------------
// Fused kernel: blocks [0,G_PA) = pass-A coarse multisplit (49 buckets ->
// runs of ~167 entries, coalesced flush); rest = MFMA gemm (R8-proven,
// verbatim).  Pass-A entry: src(16b) | dl10(10b)<<16 | coarse(6b)<<26.
// ---------------------------------------------------------------------------
__global__ __launch_bounds__(512) void k_fusedA(
    const float* __restrict__ X, const float* __restrict__ W,
    const int* __restrict__ src, const int* __restrict__ dst,
    unsigned short* __restrict__ Yb,
    unsigned* __restrict__ cpk, unsigned* __restrict__ ccur,
    unsigned* __restrict__ ovcnt, unsigned long long* __restrict__ ovlist,
    int N, int E, int nTiles) {
  __shared__ unsigned smem[CHA + 4 * 64];       // 33 KB
  const int t = threadIdx.x;

  if (blockIdx.x < G_PA) {
    // ---------------- pass-A path (proven multisplit shape) ----------------
    unsigned* lpk   = smem;                     // [CHA]  32 KB
    unsigned* cnt   = smem + CHA;               // [64]
    unsigned* offs  = cnt + 64;                 // [64]
    unsigned* cur   = offs + 64;                // [64]
    unsigned* gbase = cur + 64;                 // [64]
    const int nchunkA = (E + CHA - 1) / CHA;    // 196

    for (int c = blockIdx.x; c < nchunkA; c += G_PA) {
      const int e0   = c * CHA;
      const int ecnt = min(CHA, E - e0);

      if (t < NCB) cnt[t] = 0;
      __syncthreads();

      for (int i = t; i < ecnt; i += 512)
        atomicAdd(&cnt[(unsigned)dst[e0 + i] >> 10], 1u);
      __syncthreads();

      if (t == 0) {                             // serial scan over 49 slots
        unsigned r = 0;
        for (int i = 0; i < NCB; ++i) { offs[i] = r; cur[i] = r; r += cnt[i]; }
      }
      __syncthreads();

      for (int i = t; i < ecnt; i += 512) {
        const unsigned d  = (unsigned)dst[e0 + i];
        const unsigned cb = d >> 10;
        const unsigned p  = atomicAdd(&cur[cb], 1u);
        lpk[p] = (unsigned)src[e0 + i] | ((d & 1023u) << 16) | (cb << 26);
      }
      __syncthreads();

      if (t < NCB && cnt[t] > 0)
        gbase[t] = (unsigned)t * CCAP + atomicAdd(&ccur[t], cnt[t]);
      __syncthreads();

      for (int p = t; p < ecnt; p += 512) {     // coalesced runs ~167 entries
        const unsigned v  = lpk[p];
        const unsigned cb = v >> 26;
        const unsigned idx = gbase[cb] + ((unsigned)p - offs[cb]);
        if (idx < (cb + 1) * (unsigned)CCAP) {
          cpk[idx] = v & 0x03FFFFFFu;           // src | dl10<<16
        } else {                                // overflow (expected: never)
          const unsigned o = atomicAdd(ovcnt, 1u);
          if (o < OVCAP) {
            const unsigned node = cb * 1024u + ((v >> 16) & 1023u);
            ovlist[o] = ((unsigned long long)node << 32) | (v & 0xFFFFu);
          }
        }
      }
      __syncthreads();
    }
  } else {
    // ---------------- gemm path (R8-proven MFMA layout, verbatim) ----------
    short* Wp = (short*)smem;                   // 2048 frags x 8 bf16 = 32 KB
    for (int fid = t; fid < 2048; fid += 512) {
      const int lane = fid & 63;
      const int c    = (fid >> 6) & 3;
      const int jt   = fid >> 8;
      const int j    = jt * 16 + (lane & 15);
      const int k0   = c * 32 + (lane >> 4) * 8;
      short8 s;
      #pragma unroll
      for (int i = 0; i < 8; ++i) s[i] = f2bf(W[j * F + k0 + i]);
      *reinterpret_cast<short8*>(Wp + fid * 8) = s;
    }
    __syncthreads();

    const int lane = t & 63;
    const int tile = (blockIdx.x - G_PA) * 8 + (t >> 6);
    if (tile >= nTiles) return;
    const int row0 = tile * 16;
    const int r    = row0 + (lane & 15);
    const int k0   = (lane >> 4) * 8;

    short8 a[4];
    #pragma unroll
    for (int c = 0; c < 4; ++c) {
      if (r < N) {
        const float* p = X + (size_t)r * F + c * 32 + k0;
        const float4 x0 = *reinterpret_cast<const float4*>(p);
        const float4 x1 = *reinterpret_cast<const float4*>(p + 4);
        a[c][0] = f2bf(x0.x); a[c][1] = f2bf(x0.y);
        a[c][2] = f2bf(x0.z); a[c][3] = f2bf(x0.w);
        a[c][4] = f2bf(x1.x); a[c][5] = f2bf(x1.y);
        a[c][6] = f2bf(x1.z); a[c][7] = f2bf(x1.w);
      } else {
        #pragma unroll
        for (int i = 0; i < 8; ++i) a[c][i] = 0;
      }
    }

    #pragma unroll
    for (int jt = 0; jt < 8; ++jt) {
      f32x4 acc = {0.f, 0.f, 0.f, 0.f};
      #pragma unroll
      for (int c = 0; c < 4; ++c) {
        const short8 bfrag = *reinterpret_cast<const short8*>(
            Wp + ((jt * 4 + c) * 64 + lane) * 8);
        acc = __builtin_amdgcn_mfma_f32_16x16x32_bf16(a[c], bfrag, acc, 0, 0, 0);
      }
      const int col   = jt * 16 + (lane & 15);
      const int rbase = row0 + (lane >> 4) * 4;
      #pragma unroll
      for (int reg = 0; reg < 4; ++reg)
        if (rbase + reg < N)
          Yb[(size_t)(rbase + reg) * F + col] = (unsigned short)f2bf(acc[reg]);
    }
  }
}

// ---------------------------------------------------------------------------
// Pass B: re-split each coarse bucket into its 32 fine (node) buckets.
// Block (cb, sub) processes entries [sub*CHB, ...) of coarse bucket cb.
// Same proven multisplit shape; runs of ~256 entries = 1 KB coalesced.
// Output pk entry: src(16b) | dl5(5b)<<16 — exactly what k_reduce2 consumes.
// ---------------------------------------------------------------------------
__global__ __launch_bounds__(512) void k_partB(
    const unsigned* __restrict__ cpk, const unsigned* __restrict__ ccur,
    unsigned* __restrict__ pk, unsigned* __restrict__ gcur,
    unsigned* __restrict__ ovcnt, unsigned long long* __restrict__ ovlist) {
  const int cb  = blockIdx.x / NSUB;
  const int sub = blockIdx.x % NSUB;
  const int mA  = (int)min(ccur[cb], (unsigned)CCAP);
  const int e0  = sub * CHB;
  const int ecnt = min(CHB, mA - e0);
  if (ecnt <= 0) return;                        // uniform per block

  __shared__ unsigned lpk[CHB];                 // 32 KB
  __shared__ unsigned cnt[32], offs[32], cur[32], gbase[32];
  const int t = threadIdx.x;
  const unsigned base = (unsigned)cb * CCAP + e0;

  if (t < 32) cnt[t] = 0;
  __syncthreads();

  for (int i = t; i < ecnt; i += 512)
    atomicAdd(&cnt[(cpk[base + i] >> 21) & 31u], 1u);   // fb = dl10>>5
  __syncthreads();

  if (t == 0) {
    unsigned r = 0;
    #pragma unroll
    for (int i = 0; i < 32; ++i) { offs[i] = r; cur[i] = r; r += cnt[i]; }
  }
  __syncthreads();

  for (int i = t; i < ecnt; i += 512) {
    const unsigned v  = cpk[base + i];
    const unsigned fb = (v >> 21) & 31u;
    const unsigned p  = atomicAdd(&cur[fb], 1u);
    lpk[p] = v;
  }
  __syncthreads();

  if (t < 32 && cnt[t] > 0) {
    const unsigned gfb = (unsigned)cb * 32 + t;
    gbase[t] = gfb * CB + atomicAdd(&gcur[gfb], cnt[t]);
  }
  __syncthreads();

  for (int p = t; p < ecnt; p += 512) {         // coalesced runs ~256 entries
    const unsigned v   = lpk[p];
    const unsigned fb  = (v >> 21) & 31u;
    const unsigned gfb = (unsigned)cb * 32 + fb;
    const unsigned idx = gbase[fb] + ((unsigned)p - offs[fb]);
    if (idx < (gfb + 1) * (unsigned)CB) {
      pk[idx] = v & 0x001FFFFFu;                // src | dl5<<16
    } else {                                    // overflow (expected: never)
      const unsigned o = atomicAdd(ovcnt, 1u);
      if (o < OVCAP) {
        const unsigned node = (unsigned)cb * 1024u + ((v >> 16) & 1023u);
        ovlist[o] = ((unsigned long long)node << 32) | (v & 0xFFFFu);
      }
    }
  }
}

// ---------------------------------------------------------------------------
// Bucket-per-block gather-reduce, TWO half-row passes (R13-green VERBATIM,
// 512 threads, 4-deep pipeline).
// ---------------------------------------------------------------------------
__global__ __launch_bounds__(512) void k_reduce2(
    const unsigned short* __restrict__ Yb,   // [N][128] bf16 row-major
    const unsigned* __restrict__ pk,
    const unsigned* __restrict__ gcur,       // relative counts
    const float* __restrict__ b,
    float* __restrict__ out,                  // [N][128] f32
    int N) {
  __shared__ unsigned s_pk[CB];               // 5 KB
  __shared__ unsigned short s_src[CB];        // 2.5 KB
  __shared__ unsigned lcnt[RNODES], loffs[RNODES], lcur[RNODES];
  const int bkt = blockIdx.x % NBUCK;
  const int s   = blockIdx.x / NBUCK;         // half 0/1 (slice-major)
  const int t = threadIdx.x;
  const unsigned base = (unsigned)bkt * CB;
  const unsigned m = min(gcur[bkt], (unsigned)CB);

  for (unsigned i = t; i < m; i += 512) s_pk[i] = pk[base + i];
  if (t < RNODES) lcnt[t] = 0;
  __syncthreads();
  for (unsigned i = t; i < m; i += 512)
    atomicAdd(&lcnt[s_pk[i] >> 16], 1u);
  __syncthreads();
  if (t == 0) {
    unsigned r = 0;
    #pragma unroll
    for (int i = 0; i < RNODES; ++i) { loffs[i] = r; lcur[i] = r; r += lcnt[i]; }
  }
  __syncthreads();
  for (unsigned i = t; i < m; i += 512) {
    const unsigned v = s_pk[i];
    const unsigned p = atomicAdd(&lcur[v >> 16], 1u);
    s_src[p] = (unsigned short)(v & 0xFFFFu);
  }
  __syncthreads();

  const int lane = t & 63;
  const int g    = lane >> 4;                 // group 0..3
  const int q    = lane & 15;                 // 4-col chunk within half-row
  const int dl   = (t >> 6) * 4 + g;          // node slot 0..31
  const int v    = bkt * RNODES + dl;
  const int deg  = (int)lcnt[dl];
  const int off  = (int)loffs[dl];
  const unsigned short* Yh = Yb + s * 64;     // column offset for this half

  float acc[4];
  #pragma unroll
  for (int j = 0; j < 4; ++j) acc[j] = 0.f;

  int k = 0;
  for (; k + 3 < deg; k += 4) {               // 4 gathers in flight per group
    int sid[4];
    #pragma unroll
    for (int u = 0; u < 4; ++u) sid[u] = (int)s_src[off + k + u];
    ushort4 y[4];
    #pragma unroll
    for (int u = 0; u < 4; ++u)
      y[u] = *reinterpret_cast<const ushort4*>(
          Yh + (size_t)sid[u] * F + q * 4);
    acc[0] += (bf2f(y[0].x) + bf2f(y[1].x)) + (bf2f(y[2].x) + bf2f(y[3].x));
    acc[1] += (bf2f(y[0].y) + bf2f(y[1].y)) + (bf2f(y[2].y) + bf2f(y[3].y));
    acc[2] += (bf2f(y[0].z) + bf2f(y[1].z)) + (bf2f(y[2].z) + bf2f(y[3].z));
    acc[3] += (bf2f(y[0].w) + bf2f(y[1].w)) + (bf2f(y[2].w) + bf2f(y[3].w));
  }
  for (; k < deg; ++k) {
    const int s0 = (int)s_src[off + k];
    const ushort4 y = *reinterpret_cast<const ushort4*>(
        Yh + (size_t)s0 * F + q * 4);
    acc[0] += bf2f(y.x); acc[1] += bf2f(y.y);
    acc[2] += bf2f(y.z); acc[3] += bf2f(y.w);
  }

  if (v < N) {
    const int j = s * 64 + q * 4;
    const float4 bb = *reinterpret_cast<const float4*>(b + j);
    float4 o = make_float4(acc[0] + bb.x, acc[1] + bb.y,
                           acc[2] + bb.z, acc[3] + bb.w);
    *reinterpret_cast<float4*>(out + (size_t)v * F + j) = o;
  }
}

// ---------------------------------------------------------------------------
// Overflow fallback (green VERBATIM; expected empty).
// ---------------------------------------------------------------------------
__global__ __launch_bounds__(256) void k_overflow(
    const unsigned* __restrict__ ovcnt,
    const unsigned long long* __restrict__ ovlist,
    const unsigned short* __restrict__ Yb,
    float* __restrict__ out, int N) {
  const unsigned n = min(*ovcnt, (unsigned)OVCAP);
  const int lane = threadIdx.x & 63;
  const int w  = (int)((blockIdx.x * blockDim.x + threadIdx.x) >> 6);
  const int nw = (int)((gridDim.x * blockDim.x) >> 6);
  for (unsigned i = w; i < n; i += nw) {
    const unsigned long long e = ovlist[i];
    const unsigned s = (unsigned)(e & 0xFFFFFFFFu);
    const unsigned d = (unsigned)(e >> 32);
    const float x0 = bf2f(Yb[(size_t)s * F + lane * 2]);
    const float x1 = bf2f(Yb[(size_t)s * F + lane * 2 + 1]);
    unsafeAtomicAdd(&out[(size_t)d * F + lane * 2],     x0);
    unsafeAtomicAdd(&out[(size_t)d * F + lane * 2 + 1], x1);
  }
}

extern "C" void kernel_launch(void* const* d_in, const int* in_sizes, int n_in,
                              void* d_out, int out_size, void* d_ws, size_t ws_size,
                              hipStream_t stream) {
  const float* feat = (const float*)d_in[0];
  const int*   src  = (const int*)d_in[1];
  const int*   dst  = (const int*)d_in[2];
  const float* W    = (const float*)d_in[3];
  const float* b    = (const float*)d_in[4];
  float*       out  = (float*)d_out;

  const int N = in_sizes[0] / F;   // 50000
  const int E = in_sizes[1];       // 1600000

  char* w = (char*)d_ws;
  auto alloc = [&](size_t bytes) {
    char* p = w; w += (bytes + 255) & ~(size_t)255; return p;
  };
  unsigned short*     Yb      = (unsigned short*)alloc((size_t)N * F * 2);
  unsigned*           cpk     = (unsigned*)alloc((size_t)NCB * CCAP * 4);   // 6.7 MB
  unsigned*           pk      = (unsigned*)alloc((size_t)NBUCK * CB * 4);   // 8.0 MB
  unsigned*           gcur    = (unsigned*)alloc((size_t)(NBUCK + 1 + NCB) * 4);
  unsigned*           ovcnt   = gcur + NBUCK;            // adjacent for memset
  unsigned*           ccur    = ovcnt + 1;
  unsigned long long* ovlist  = (unsigned long long*)alloc((size_t)OVCAP * 8);

  // gcur + ovcnt + ccur zeroed in one memset node.
  hipMemsetAsync(gcur, 0, (size_t)(NBUCK + 1 + NCB) * 4, stream);

  const int nTiles = (N + 15) / 16;                       // 3125
  const int gGemm  = (nTiles + 7) / 8;                    // 391
  k_fusedA<<<G_PA + gGemm, 512, 0, stream>>>(
      feat, W, src, dst, Yb, cpk, ccur, ovcnt, ovlist, N, E, nTiles);

  k_partB<<<NCB * NSUB, 512, 0, stream>>>(
      cpk, ccur, pk, gcur, ovcnt, ovlist);

  k_reduce2<<<2 * NBUCK, 512, 0, stream>>>(Yb, pk, gcur, b, out, N);

  k_overflow<<<16, 256, 0, stream>>>(ovcnt, ovlist, Yb, out, N);
}

// Round 16
// 80.466 us; speedup vs baseline: 1.1503x; 1.1503x over previous
//
#include <hip/hip_runtime.h>

#define F      128
#define RSH    5            // 32 nodes per bucket
#define RNODES 32
#define NBUCK  1563         // ceil(50000/32) — N fixed at 50000
#define CB     1280         // bucket capacity (mean 1024, +8 sigma)
#define CH     4096         // edges per partition chunk (R13-proven)
#define OVCAP  65536
#define G_PART 391          // partition blocks (= nchunk for E=1.6M, CH=4096)

typedef __attribute__((ext_vector_type(8))) short short8;            // 8 bf16
typedef __attribute__((ext_vector_type(4))) float f32x4;             // MFMA C/D

__device__ inline short f2bf(float f) {        // fp32 -> bf16 RNE
  unsigned u = __float_as_uint(f);
  u += 0x7fff + ((u >> 16) & 1);
  return (short)(u >> 16);
}
__device__ inline float bf2f(unsigned short u) {
  return __uint_as_float((unsigned)u << 16);
}

// ---------------------------------------------------------------------------
// Fused kernel (R13-green VERBATIM): blocks [0,G_PART) = multisplit
// partition; rest = MFMA gemm.
// ---------------------------------------------------------------------------
__global__ __launch_bounds__(512) void k_fused(
    const float* __restrict__ X, const float* __restrict__ W,
    const int* __restrict__ src, const int* __restrict__ dst,
    unsigned short* __restrict__ Yb,
    unsigned* __restrict__ pk, unsigned* __restrict__ gcur,
    unsigned* __restrict__ ovcnt, unsigned long long* __restrict__ ovlist,
    int N, int E, int nTiles) {
  __shared__ unsigned smem[CH + 3 * NBUCK];     // 8785 u32 = 35.1 KB
  const int t = threadIdx.x;

  if (blockIdx.x < G_PART) {
    // ---------------- partition path (R4-proven logic) ----------------
    unsigned* lpk   = smem;                     // [CH]
    unsigned* cnt   = smem + CH;                // [NBUCK] (becomes gbase)
    unsigned* offs  = cnt + NBUCK;              // [NBUCK]
    unsigned* cur   = offs + NBUCK;             // [NBUCK] (also scan scratch)
    const int nchunk = (E + CH - 1) / CH;

    for (int c = blockIdx.x; c < nchunk; c += G_PART) {
      const int e0   = c * CH;
      const int ecnt = min(CH, E - e0);

      for (int i = t; i < NBUCK; i += 512) cnt[i] = 0;
      __syncthreads();

      for (int i = t; i < ecnt; i += 512)
        atomicAdd(&cnt[(unsigned)dst[e0 + i] >> RSH], 1u);
      __syncthreads();

      unsigned lv0, lv1, lv2, lv3;
      {
        const int i0 = t * 4;
        lv0 = (i0 + 0 < NBUCK) ? cnt[i0 + 0] : 0;
        lv1 = (i0 + 1 < NBUCK) ? cnt[i0 + 1] : 0;
        lv2 = (i0 + 2 < NBUCK) ? cnt[i0 + 2] : 0;
        lv3 = (i0 + 3 < NBUCK) ? cnt[i0 + 3] : 0;
      }
      cur[t] = lv0 + lv1 + lv2 + lv3;
      __syncthreads();
      for (int d2 = 1; d2 < 512; d2 <<= 1) {
        const unsigned add = (t >= d2) ? cur[t - d2] : 0;
        __syncthreads();
        cur[t] += add;
        __syncthreads();
      }
      unsigned ebase = (t > 0) ? cur[t - 1] : 0;
      __syncthreads();
      {
        const int i0 = t * 4;
        if (i0 + 0 < NBUCK) { offs[i0 + 0] = ebase; cur[i0 + 0] = ebase; ebase += lv0; }
        if (i0 + 1 < NBUCK) { offs[i0 + 1] = ebase; cur[i0 + 1] = ebase; ebase += lv1; }
        if (i0 + 2 < NBUCK) { offs[i0 + 2] = ebase; cur[i0 + 2] = ebase; ebase += lv2; }
        if (i0 + 3 < NBUCK) { offs[i0 + 3] = ebase; cur[i0 + 3] = ebase; ebase += lv3; }
      }
      __syncthreads();

      for (int i = t; i < ecnt; i += 512) {
        const unsigned d = (unsigned)dst[e0 + i];
        const unsigned b = d >> RSH;
        const unsigned p = atomicAdd(&cur[b], 1u);
        lpk[p] = (unsigned)src[e0 + i] | ((d & (RNODES - 1)) << 16) | (b << 21);
      }
      __syncthreads();

      // reserve global space: cnt[i] becomes gbase[i] IN PLACE.
      for (int i = t; i < NBUCK; i += 512) {
        const unsigned c0 = cnt[i];
        if (c0 > 0) cnt[i] = (unsigned)i * CB + atomicAdd(&gcur[i], c0);
      }
      __syncthreads();

      for (int p = t; p < ecnt; p += 512) {
        const unsigned v = lpk[p];
        const unsigned b = v >> 21;
        const unsigned idx = cnt[b] + ((unsigned)p - offs[b]);
        if (idx < (b + 1) * (unsigned)CB) {
          pk[idx] = v & 0x1FFFFFu;
        } else {                                // overflow (expected: never)
          const unsigned o = atomicAdd(ovcnt, 1u);
          if (o < OVCAP) {
            const unsigned s  = v & 0xFFFFu;
            const unsigned dl = (v >> 16) & (RNODES - 1);
            ovlist[o] = ((unsigned long long)(b * RNODES + dl) << 32) | s;
          }
        }
      }
      __syncthreads();
    }
  } else {
    // ---------------- gemm path (R8-proven MFMA layout) ----------------
    short* Wp = (short*)smem;                   // 2048 frags x 8 bf16 = 32 KB
    for (int fid = t; fid < 2048; fid += 512) {
      const int lane = fid & 63;
      const int c    = (fid >> 6) & 3;
      const int jt   = fid >> 8;
      const int j    = jt * 16 + (lane & 15);
      const int k0   = c * 32 + (lane >> 4) * 8;
      short8 s;
      #pragma unroll
      for (int i = 0; i < 8; ++i) s[i] = f2bf(W[j * F + k0 + i]);
      *reinterpret_cast<short8*>(Wp + fid * 8) = s;
    }
    __syncthreads();

    const int lane = t & 63;
    const int tile = (blockIdx.x - G_PART) * 8 + (t >> 6);
    if (tile >= nTiles) return;
    const int row0 = tile * 16;
    const int r    = row0 + (lane & 15);
    const int k0   = (lane >> 4) * 8;

    short8 a[4];
    #pragma unroll
    for (int c = 0; c < 4; ++c) {
      if (r < N) {
        const float* p = X + (size_t)r * F + c * 32 + k0;
        const float4 x0 = *reinterpret_cast<const float4*>(p);
        const float4 x1 = *reinterpret_cast<const float4*>(p + 4);
        a[c][0] = f2bf(x0.x); a[c][1] = f2bf(x0.y);
        a[c][2] = f2bf(x0.z); a[c][3] = f2bf(x0.w);
        a[c][4] = f2bf(x1.x); a[c][5] = f2bf(x1.y);
        a[c][6] = f2bf(x1.z); a[c][7] = f2bf(x1.w);
      } else {
        #pragma unroll
        for (int i = 0; i < 8; ++i) a[c][i] = 0;
      }
    }

    #pragma unroll
    for (int jt = 0; jt < 8; ++jt) {
      f32x4 acc = {0.f, 0.f, 0.f, 0.f};
      #pragma unroll
      for (int c = 0; c < 4; ++c) {
        const short8 bfrag = *reinterpret_cast<const short8*>(
            Wp + ((jt * 4 + c) * 64 + lane) * 8);
        acc = __builtin_amdgcn_mfma_f32_16x16x32_bf16(a[c], bfrag, acc, 0, 0, 0);
      }
      const int col   = jt * 16 + (lane & 15);
      const int rbase = row0 + (lane >> 4) * 4;
      #pragma unroll
      for (int reg = 0; reg < 4; ++reg)
        if (rbase + reg < N)
          Yb[(size_t)(rbase + reg) * F + col] = (unsigned short)f2bf(acc[reg]);
    }
  }
}

// ---------------------------------------------------------------------------
// Bucket-per-block gather-reduce, TWO half-row passes (R13-green VERBATIM:
// 512 threads, 4-deep pipeline).
// ---------------------------------------------------------------------------
__global__ __launch_bounds__(512) void k_reduce2(
    const unsigned short* __restrict__ Yb,   // [N][128] bf16 row-major
    const unsigned* __restrict__ pk,
    const unsigned* __restrict__ gcur,       // relative counts
    const float* __restrict__ b,
    float* __restrict__ out,                  // [N][128] f32
    int N) {
  __shared__ unsigned s_pk[CB];               // 5 KB
  __shared__ unsigned short s_src[CB];        // 2.5 KB
  __shared__ unsigned lcnt[RNODES], loffs[RNODES], lcur[RNODES];
  const int bkt = blockIdx.x % NBUCK;
  const int s   = blockIdx.x / NBUCK;         // half 0/1 (slice-major)
  const int t = threadIdx.x;
  const unsigned base = (unsigned)bkt * CB;
  const unsigned m = min(gcur[bkt], (unsigned)CB);

  for (unsigned i = t; i < m; i += 512) s_pk[i] = pk[base + i];
  if (t < RNODES) lcnt[t] = 0;
  __syncthreads();
  for (unsigned i = t; i < m; i += 512)
    atomicAdd(&lcnt[s_pk[i] >> 16], 1u);
  __syncthreads();
  if (t == 0) {
    unsigned r = 0;
    #pragma unroll
    for (int i = 0; i < RNODES; ++i) { loffs[i] = r; lcur[i] = r; r += lcnt[i]; }
  }
  __syncthreads();
  for (unsigned i = t; i < m; i += 512) {
    const unsigned v = s_pk[i];
    const unsigned p = atomicAdd(&lcur[v >> 16], 1u);
    s_src[p] = (unsigned short)(v & 0xFFFFu);
  }
  __syncthreads();

  const int lane = t & 63;
  const int g    = lane >> 4;                 // group 0..3
  const int q    = lane & 15;                 // 4-col chunk within half-row
  const int dl   = (t >> 6) * 4 + g;          // node slot 0..31
  const int v    = bkt * RNODES + dl;
  const int deg  = (int)lcnt[dl];
  const int off  = (int)loffs[dl];
  const unsigned short* Yh = Yb + s * 64;     // column offset for this half

  float acc[4];
  #pragma unroll
  for (int j = 0; j < 4; ++j) acc[j] = 0.f;

  int k = 0;
  for (; k + 3 < deg; k += 4) {               // 4 gathers in flight per group
    int sid[4];
    #pragma unroll
    for (int u = 0; u < 4; ++u) sid[u] = (int)s_src[off + k + u];
    ushort4 y[4];
    #pragma unroll
    for (int u = 0; u < 4; ++u)
      y[u] = *reinterpret_cast<const ushort4*>(
          Yh + (size_t)sid[u] * F + q * 4);
    acc[0] += (bf2f(y[0].x) + bf2f(y[1].x)) + (bf2f(y[2].x) + bf2f(y[3].x));
    acc[1] += (bf2f(y[0].y) + bf2f(y[1].y)) + (bf2f(y[2].y) + bf2f(y[3].y));
    acc[2] += (bf2f(y[0].z) + bf2f(y[1].z)) + (bf2f(y[2].z) + bf2f(y[3].z));
    acc[3] += (bf2f(y[0].w) + bf2f(y[1].w)) + (bf2f(y[2].w) + bf2f(y[3].w));
  }
  for (; k < deg; ++k) {
    const int s0 = (int)s_src[off + k];
    const ushort4 y = *reinterpret_cast<const ushort4*>(
        Yh + (size_t)s0 * F + q * 4);
    acc[0] += bf2f(y.x); acc[1] += bf2f(y.y);
    acc[2] += bf2f(y.z); acc[3] += bf2f(y.w);
  }

  if (v < N) {
    const int j = s * 64 + q * 4;
    const float4 bb = *reinterpret_cast<const float4*>(b + j);
    float4 o = make_float4(acc[0] + bb.x, acc[1] + bb.y,
                           acc[2] + bb.z, acc[3] + bb.w);
    *reinterpret_cast<float4*>(out + (size_t)v * F + j) = o;
  }
}

// ---------------------------------------------------------------------------
// Overflow fallback (R13-green VERBATIM; expected empty).
// ---------------------------------------------------------------------------
__global__ __launch_bounds__(256) void k_overflow(
    const unsigned* __restrict__ ovcnt,
    const unsigned long long* __restrict__ ovlist,
    const unsigned short* __restrict__ Yb,
    float* __restrict__ out, int N) {
  const unsigned n = min(*ovcnt, (unsigned)OVCAP);
  const int lane = threadIdx.x & 63;
  const int w  = (int)((blockIdx.x * blockDim.x + threadIdx.x) >> 6);
  const int nw = (int)((gridDim.x * blockDim.x) >> 6);
  for (unsigned i = w; i < n; i += nw) {
    const unsigned long long e = ovlist[i];
    const unsigned s = (unsigned)(e & 0xFFFFFFFFu);
    const unsigned d = (unsigned)(e >> 32);
    const float x0 = bf2f(Yb[(size_t)s * F + lane * 2]);
    const float x1 = bf2f(Yb[(size_t)s * F + lane * 2 + 1]);
    unsafeAtomicAdd(&out[(size_t)d * F + lane * 2],     x0);
    unsafeAtomicAdd(&out[(size_t)d * F + lane * 2 + 1], x1);
  }
}

extern "C" void kernel_launch(void* const* d_in, const int* in_sizes, int n_in,
                              void* d_out, int out_size, void* d_ws, size_t ws_size,
                              hipStream_t stream) {
  const float* feat = (const float*)d_in[0];
  const int*   src  = (const int*)d_in[1];
  const int*   dst  = (const int*)d_in[2];
  const float* W    = (const float*)d_in[3];
  const float* b    = (const float*)d_in[4];
  float*       out  = (float*)d_out;

  const int N = in_sizes[0] / F;   // 50000
  const int E = in_sizes[1];       // 1600000

  char* w = (char*)d_ws;
  auto alloc = [&](size_t bytes) {
    char* p = w; w += (bytes + 255) & ~(size_t)255; return p;
  };
  unsigned short*     Yb      = (unsigned short*)alloc((size_t)N * F * 2);
  unsigned*           pk      = (unsigned*)alloc((size_t)NBUCK * CB * 4);
  unsigned*           gcur    = (unsigned*)alloc((size_t)(NBUCK + 1) * 4);
  unsigned*           ovcnt   = gcur + NBUCK;            // adjacent for memset
  unsigned long long* ovlist  = (unsigned long long*)alloc((size_t)OVCAP * 8);

  // gcur (relative counts) + ovcnt zeroed in one memset node.
  hipMemsetAsync(gcur, 0, (size_t)(NBUCK + 1) * 4, stream);

  const int nTiles = (N + 15) / 16;                       // 3125
  const int gGemm  = (nTiles + 7) / 8;                    // 391
  k_fused<<<G_PART + gGemm, 512, 0, stream>>>(
      feat, W, src, dst, Yb, pk, gcur, ovcnt, ovlist, N, E, nTiles);

  k_reduce2<<<2 * NBUCK, 512, 0, stream>>>(Yb, pk, gcur, b, out, N);

  k_overflow<<<16, 256, 0, stream>>>(ovcnt, ovlist, Yb, out, N);
}